// Round 12
// baseline (428.523 us; speedup 1.0000x reference)
//
#include <hip/hip_runtime.h>
#include <hip/hip_bf16.h>

#define ALPHA 0.2f

typedef __attribute__((ext_vector_type(8)))  __bf16 bf16x8;
typedef int          i32x2 __attribute__((ext_vector_type(2)));
typedef float        f32x2 __attribute__((ext_vector_type(2)));
typedef float        f32x4 __attribute__((ext_vector_type(4)));
typedef unsigned int u32x4 __attribute__((ext_vector_type(4)));

static __device__ __forceinline__ unsigned short bf16bits(float v) {
    __bf16 b = (__bf16)v;
    unsigned short u;
    __builtin_memcpy(&u, &b, 2);
    return u;
}

// ---------- Kernel 1: h = x*W ; f1 = h@a1 ; f2 = h@a2 ; hB = 16x16x32 B-fragment-packed h ----------
// (unchanged from R8/R11 — hB layout identical)
__global__ __launch_bounds__(256) void gat_prep(
    const float* __restrict__ x, const float* __restrict__ W, const float* __restrict__ a,
    float* __restrict__ f1, float* __restrict__ f2, unsigned short* __restrict__ hB,
    float* __restrict__ ws_acc)
{
    __shared__ unsigned short lh[32][136];   // [j-local][f]
    int t = threadIdx.x;
    int i0 = blockIdx.x * 32;
    if (blockIdx.x == 0 && t < 128) ws_acc[t] = 0.0f;

    int row = t >> 3, q = t & 7;             // 8 threads per row, 16 f each
    int i = i0 + row;
    const float4* xp  = (const float4*)(x + (size_t)i * 128 + q * 16);
    const float4* wp  = (const float4*)(W + (size_t)i * 128 + q * 16);
    const float4* a1p = (const float4*)(a + q * 16);
    const float4* a2p = (const float4*)(a + 128 + q * 16);
    float p1 = 0.f, p2 = 0.f;
    #pragma unroll
    for (int jj = 0; jj < 4; ++jj) {
        float4 xv = xp[jj], wv = wp[jj], a1v = a1p[jj], a2v = a2p[jj];
        float h0 = xv.x * wv.x, h1 = xv.y * wv.y, h2 = xv.z * wv.z, h3 = xv.w * wv.w;
        p1 += h0 * a1v.x + h1 * a1v.y + h2 * a1v.z + h3 * a1v.w;
        p2 += h0 * a2v.x + h1 * a2v.y + h2 * a2v.z + h3 * a2v.w;
        int fb = q * 16 + jj * 4;
        lh[row][fb + 0] = bf16bits(h0);
        lh[row][fb + 1] = bf16bits(h1);
        lh[row][fb + 2] = bf16bits(h2);
        lh[row][fb + 3] = bf16bits(h3);
    }
    p1 += __shfl_xor(p1, 1); p1 += __shfl_xor(p1, 2); p1 += __shfl_xor(p1, 4);
    p2 += __shfl_xor(p2, 1); p2 += __shfl_xor(p2, 2); p2 += __shfl_xor(p2, 4);
    if (q == 0) { f1[i] = p1; f2[i] = p2; }
    __syncthreads();

    int ftl = t >> 5, s0 = t & 31;
    size_t fragbase = ((size_t)blockIdx.x * 8 + ftl) * 512;
    #pragma unroll
    for (int hw = 0; hw < 2; ++hw) {
        int s = s0 + hw * 32;
        int jl = (s >> 4) * 8;
        int f = ftl * 16 + (s & 15);
        unsigned int p[4];
        #pragma unroll
        for (int k = 0; k < 4; ++k) {
            unsigned int lo = lh[jl + 2 * k][f];
            unsigned int hi = lh[jl + 2 * k + 1][f];
            p[k] = lo | (hi << 16);
        }
        u32x4 v = {p[0], p[1], p[2], p[3]};
        *(u32x4*)(hB + fragbase + s * 8) = v;
    }
}

// ---------- Kernel 2: M=32 wave-autonomous fused attention ----------
// R12 vs R11: wave owns 32 rows (two 16-row m-tiles) sharing ONE B-stream — B traffic
// halves (1 GB -> 512 MB), L1 bytes/area -40%. Chunk = 32r x 128j (adj i32x2, 64 VGPR).
// den computed by an extra ones-B MFMA on the staged wg tile (saves 32 VGPR; bf16-exact).
// f1 forced to SGPR via readfirstlane. Grid 512 = 256 gid x 2 jh, 256 thr (4 waves),
// wave w owns j-quarter of the half: 8 chunks of 128 j. K-loop skeleton = R8-verified.
__global__ __launch_bounds__(256, 2) void gat_main(
    const int* __restrict__ adj, const float* __restrict__ x,
    const float* __restrict__ W2, const float* __restrict__ f1g,
    const float* __restrict__ f2g, const unsigned short* __restrict__ hB,
    float* __restrict__ hp_part, float* __restrict__ den_part,
    float* __restrict__ ws_acc)
{
    __shared__ unsigned short tile[4][32][136];   // 34.8 KB per-wave wg tiles (32r x 128j)
    __shared__ float rs_s[4][32];

    int tid = threadIdx.x;
    int w = tid >> 6, l = tid & 63;
    int gid = blockIdx.x >> 1, jh = blockIdx.x & 1;
    int i0 = gid * 32;

    float f1r[32];
    #pragma unroll
    for (int r = 0; r < 32; ++r)
        f1r[r] = __uint_as_float(__builtin_amdgcn_readfirstlane(__float_as_uint(f1g[i0 + r])));

    float rs[32];
    #pragma unroll
    for (int r = 0; r < 32; ++r) rs[r] = 0.f;
    f32x4 acc[2][8] = {};
    f32x4 accd[2] = {};

    const int jbase = jh * 4096 + w * 1024;
    const int* arow = adj + (size_t)i0 * 8192 + jbase + l * 2;
    const float* f2p = f2g + jbase + l * 2;
    const float* w2p = W2 + jbase + l * 2;

    i32x2 adjreg[32];
    f32x2 f2v, w2v;
    auto issue = [&](int c) {
        int jo = c * 128;
        f2v = *(const f32x2*)(f2p + jo);
        w2v = *(const f32x2*)(w2p + jo);
        #pragma unroll
        for (int r = 0; r < 32; ++r)
            adjreg[r] = __builtin_nontemporal_load(
                (const i32x2*)(arow + (size_t)r * 8192 + jo));
    };
    issue(0);

    bf16x8 ones;
    #pragma unroll
    for (int e = 0; e < 8; ++e) ones[e] = (__bf16)1.0f;

    const unsigned short* hBw = hB + (size_t)jbase * 128 + l * 8;
    const unsigned short* ap0 = &tile[w][l & 15][(l >> 4) * 8];
    const unsigned short* ap1 = &tile[w][16 + (l & 15)][(l >> 4) * 8];

    for (int c = 0; c < 8; ++c) {
        // ---- consume chunk c: wg -> private LDS tile (32 rows x 128 j) ----
        f32x2 cf2 = f2v, cw2 = w2v;
        #pragma unroll
        for (int r = 0; r < 32; ++r) {
            i32x2 ad = adjreg[r];
            float g[2];
            #pragma unroll
            for (int e = 0; e < 2; ++e) {
                float tt = f1r[r] + cf2[e];
                float lr = fmaxf(tt, ALPHA * tt);     // leakyrelu
                float ex = __expf(lr);
                float gg = (ad[e] != 0) ? ex : 0.0f;
                g[e] = gg;
                rs[r] += (ad[e] != 0) ? cw2[e] : 0.0f;
            }
            unsigned int pk = bf16bits(g[0]) | ((unsigned int)bf16bits(g[1]) << 16);
            *(unsigned int*)&tile[w][r][l * 2] = pk;
        }
        // ---- prefetch chunk c+1 adj/scalars ----
        if (c < 7) issue(c + 1);

        // ---- MFMA chunk c: 4 k-steps x 8 f-tiles x 2 m-tiles; B dbuf in 4-frag halves ----
        const unsigned short* bp = hBw + (size_t)c * 16384;
        bf16x8 bbuf[2][4];
        #pragma unroll
        for (int q = 0; q < 4; ++q)
            bbuf[0][q] = *(const bf16x8*)(bp + q * 512);
        bf16x8 af0, af1;
        #pragma unroll
        for (int hi = 0; hi < 8; ++hi) {
            int cur = hi & 1;
            if (hi < 7) {
                const unsigned short* nb = bp + (size_t)((hi + 1) >> 1) * 4096
                                              + (size_t)((hi + 1) & 1) * 2048;
                #pragma unroll
                for (int q = 0; q < 4; ++q)
                    bbuf[cur ^ 1][q] = *(const bf16x8*)(nb + q * 512);
            }
            if ((hi & 1) == 0) {
                int ks = hi >> 1;
                af0 = *(const bf16x8*)(ap0 + ks * 32);
                af1 = *(const bf16x8*)(ap1 + ks * 32);
                accd[0] = __builtin_amdgcn_mfma_f32_16x16x32_bf16(af0, ones, accd[0], 0, 0, 0);
                accd[1] = __builtin_amdgcn_mfma_f32_16x16x32_bf16(af1, ones, accd[1], 0, 0, 0);
            }
            #pragma unroll
            for (int q = 0; q < 4; ++q) {
                int ftg = (hi & 1) * 4 + q;
                acc[0][ftg] = __builtin_amdgcn_mfma_f32_16x16x32_bf16(af0, bbuf[cur][q], acc[0][ftg], 0, 0, 0);
                acc[1][ftg] = __builtin_amdgcn_mfma_f32_16x16x32_bf16(af1, bbuf[cur][q], acc[1][ftg], 0, 0, 0);
            }
        }
    }

    // ---- rs lane reduction -> rs_s ----
    #pragma unroll
    for (int r = 0; r < 32; ++r) {
        float rr = rs[r];
        #pragma unroll
        for (int off = 1; off < 64; off <<= 1) rr += __shfl_xor(rr, off);
        if (l == 0) rs_s[w][r] = rr;
    }

    // ---- 4-way j-split acc reduction via tile-as-float (serial rounds, race-safe) ----
    __syncthreads();
    float* fb = (float*)&tile[0][0][0];
    float* av = (float*)acc;     // 64 floats
    float* avd = (float*)accd;   // 8 floats
    #pragma unroll 1
    for (int wsrc = 1; wsrc < 4; ++wsrc) {
        if (w == wsrc) {
            #pragma unroll
            for (int j = 0; j < 64; ++j) fb[j * 64 + l] = av[j];
            #pragma unroll
            for (int j = 0; j < 8; ++j) fb[(64 + j) * 64 + l] = avd[j];
        }
        __syncthreads();
        if (w == 0) {
            #pragma unroll
            for (int j = 0; j < 64; ++j) av[j] += fb[j * 64 + l];
            #pragma unroll
            for (int j = 0; j < 8; ++j) avd[j] += fb[(64 + j) * 64 + l];
        }
        __syncthreads();
    }

    if (w == 0) {
        int q = l >> 4, col = l & 15;
        float* hpb = hp_part + ((size_t)jh * 8192 + i0) * 128;
        #pragma unroll
        for (int m = 0; m < 2; ++m) {
            #pragma unroll
            for (int reg = 0; reg < 4; ++reg) {
                int row = m * 16 + q * 4 + reg;
                #pragma unroll
                for (int ft = 0; ft < 8; ++ft)
                    __builtin_nontemporal_store(acc[m][ft][reg],
                        hpb + (size_t)row * 128 + ft * 16 + col);
                if (col == 0)
                    den_part[(size_t)jh * 8192 + i0 + row] = accd[m][reg];
            }
        }
    } else if (w == 1) {
        // out-path partial: sum_i rs[i] * x[i][:] over this block's 32 rows (linear in rs)
        float px = 0.f, py = 0.f;
        #pragma unroll
        for (int r = 0; r < 32; ++r) {
            float rm = rs_s[0][r] + rs_s[1][r] + rs_s[2][r] + rs_s[3][r];
            const float* xr = x + (size_t)(i0 + r) * 128;
            px += rm * xr[l];
            py += rm * xr[l + 64];
        }
        atomicAdd(ws_acc + l, px);
        atomicAdd(ws_acc + l + 64, py);
    }
}

// ---------- Kernel 2b: merge j-half partials, normalize ----------
__global__ __launch_bounds__(256) void gat_norm(
    const float* __restrict__ hp_part, const float* __restrict__ den_part,
    float* __restrict__ hp)
{
    int t = threadIdx.x;
    int row = blockIdx.x * 32 + (t >> 3);
    int f0 = (t & 7) * 16;
    float d = den_part[row] + den_part[8192 + row];
    float inv = (d != 0.f) ? 1.0f / d : 0.f;
    const f32x4* p0 = (const f32x4*)(hp_part + (size_t)row * 128 + f0);
    const f32x4* p1 = (const f32x4*)(hp_part + (size_t)(8192 + row) * 128 + f0);
    f32x4* o = (f32x4*)(hp + (size_t)row * 128 + f0);
    #pragma unroll
    for (int k = 0; k < 4; ++k) {
        f32x4 v = (p0[k] + p1[k]);
        o[k] = v * inv;
    }
}

// ---------- Kernel 3: elu epilogue ----------
__global__ __launch_bounds__(128) void gat_finish(const float* __restrict__ ws_acc,
                                                  float* __restrict__ out)
{
    int t = threadIdx.x;
    float v = ws_acc[t];
    out[t] = (v > 0.f) ? v : (__expf(v) - 1.0f);
}

extern "C" void kernel_launch(void* const* d_in, const int* in_sizes, int n_in,
                              void* d_out, int out_size, void* d_ws, size_t ws_size,
                              hipStream_t stream) {
    const float* x   = (const float*)d_in[0];
    const int*   adj = (const int*)d_in[1];
    const float* W   = (const float*)d_in[2];
    const float* a   = (const float*)d_in[3];
    const float* W2  = (const float*)d_in[4];
    float* out = (float*)d_out;              // [0:128] elu out, [128:] h_prime [8192][128]

    float* wsf     = (float*)d_ws;
    float* ws_acc  = wsf;                        // 128 floats
    float* f1      = wsf + 128;                  // 8192
    float* f2      = wsf + 128 + 8192;           // 8192
    unsigned short* hB = (unsigned short*)(wsf + 128 + 2 * 8192);  // 1M shorts (2 MB)
    float* hp_part = wsf + 128 + 2 * 8192 + 524288;   // 2*8192*128 f32 = 8 MB
    float* den_part = hp_part + 2 * 8192 * 128;       // 2*8192 f32

    gat_prep<<<256, 256, 0, stream>>>(x, W, a, f1, f2, hB, ws_acc);
    gat_main<<<512, 256, 0, stream>>>(adj, x, W2, f1, f2, hB, hp_part, den_part, ws_acc);
    gat_norm<<<256, 256, 0, stream>>>(hp_part, den_part, out + 128);
    gat_finish<<<1, 128, 0, stream>>>(ws_acc, out);
}

// Round 13
// 397.544 us; speedup vs baseline: 1.0779x; 1.0779x over previous
//
#include <hip/hip_runtime.h>
#include <hip/hip_bf16.h>

#define ALPHA 0.2f

typedef __attribute__((ext_vector_type(8)))  __bf16 bf16x8;
typedef int          i32x4 __attribute__((ext_vector_type(4)));
typedef float        f32x4 __attribute__((ext_vector_type(4)));
typedef unsigned int u32x4 __attribute__((ext_vector_type(4)));

static __device__ __forceinline__ unsigned short bf16bits(float v) {
    __bf16 b = (__bf16)v;
    unsigned short u;
    __builtin_memcpy(&u, &b, 2);
    return u;
}

// ---------- Kernel 1: h = x*W ; f1 = h@a1 ; f2 = h@a2 ; hB = 16x16x32 B-fragment-packed h ----------
// (unchanged from R8 — hB layout identical)
__global__ __launch_bounds__(256) void gat_prep(
    const float* __restrict__ x, const float* __restrict__ W, const float* __restrict__ a,
    float* __restrict__ f1, float* __restrict__ f2, unsigned short* __restrict__ hB,
    float* __restrict__ ws_acc)
{
    __shared__ unsigned short lh[32][136];   // [j-local][f]
    int t = threadIdx.x;
    int i0 = blockIdx.x * 32;
    if (blockIdx.x == 0 && t < 128) ws_acc[t] = 0.0f;

    int row = t >> 3, q = t & 7;             // 8 threads per row, 16 f each
    int i = i0 + row;
    const float4* xp  = (const float4*)(x + (size_t)i * 128 + q * 16);
    const float4* wp  = (const float4*)(W + (size_t)i * 128 + q * 16);
    const float4* a1p = (const float4*)(a + q * 16);
    const float4* a2p = (const float4*)(a + 128 + q * 16);
    float p1 = 0.f, p2 = 0.f;
    #pragma unroll
    for (int jj = 0; jj < 4; ++jj) {
        float4 xv = xp[jj], wv = wp[jj], a1v = a1p[jj], a2v = a2p[jj];
        float h0 = xv.x * wv.x, h1 = xv.y * wv.y, h2 = xv.z * wv.z, h3 = xv.w * wv.w;
        p1 += h0 * a1v.x + h1 * a1v.y + h2 * a1v.z + h3 * a1v.w;
        p2 += h0 * a2v.x + h1 * a2v.y + h2 * a2v.z + h3 * a2v.w;
        int fb = q * 16 + jj * 4;
        lh[row][fb + 0] = bf16bits(h0);
        lh[row][fb + 1] = bf16bits(h1);
        lh[row][fb + 2] = bf16bits(h2);
        lh[row][fb + 3] = bf16bits(h3);
    }
    p1 += __shfl_xor(p1, 1); p1 += __shfl_xor(p1, 2); p1 += __shfl_xor(p1, 4);
    p2 += __shfl_xor(p2, 1); p2 += __shfl_xor(p2, 2); p2 += __shfl_xor(p2, 4);
    if (q == 0) { f1[i] = p1; f2[i] = p2; }
    __syncthreads();

    int ftl = t >> 5, s0 = t & 31;
    size_t fragbase = ((size_t)blockIdx.x * 8 + ftl) * 512;
    #pragma unroll
    for (int hw = 0; hw < 2; ++hw) {
        int s = s0 + hw * 32;
        int jl = (s >> 4) * 8;
        int f = ftl * 16 + (s & 15);
        unsigned int p[4];
        #pragma unroll
        for (int k = 0; k < 4; ++k) {
            unsigned int lo = lh[jl + 2 * k][f];
            unsigned int hi = lh[jl + 2 * k + 1][f];
            p[k] = lo | (hi << 16);
        }
        u32x4 v = {p[0], p[1], p[2], p[3]};
        *(u32x4*)(hB + fragbase + s * 8) = v;
    }
}

// ---------- Kernel 2: tall-block wave-autonomous fused attention ----------
// R13 vs R8: per-CU line-traffic cut. Block = 512 thr = 8 waves = 4 row-groups (M) x 2
// j-slices; block covers 64 rows x 4096 j (jh = blockIdx.x&1 picks the j-half). Each
// wave's job is EXACTLY R8's verified unit: 16 rows x 2048 j as 8 chunks of 256 j,
// same consume loop, same B dbuf MFMA. Per-CU processed traffic drops 5 MB -> 2 MB
// (B re-read per 64 rows instead of per 16; same-js waves hit the same B-tiles in L1).
// Epilogue: pairwise js reduction; un-normalized partials + gat_norm (R12-proven).
__global__ __launch_bounds__(512, 2) void gat_main(
    const int* __restrict__ adj, const float* __restrict__ x,
    const float* __restrict__ W2, const float* __restrict__ f1g,
    const float* __restrict__ f2g, const unsigned short* __restrict__ hB,
    float* __restrict__ hp_part, float* __restrict__ den_part,
    float* __restrict__ ws_acc)
{
    __shared__ unsigned short tile[8][16][264];   // 67.6 KB, per-wave private wg tiles
    __shared__ float den_s[8][16], rs_s[8][16];

    int tid = threadIdx.x;
    int w = tid >> 6, l = tid & 63;
    int mg = w >> 1, js = w & 1;
    int gid = blockIdx.x >> 1, jh = blockIdx.x & 1;
    int i0 = gid * 64;                 // block's 64 rows
    int iw = i0 + mg * 16;             // wave's 16 rows

    float f1r[16];
    #pragma unroll
    for (int r = 0; r < 16; ++r) f1r[r] = f1g[iw + r];

    float den[16], rs[16];
    #pragma unroll
    for (int r = 0; r < 16; ++r) { den[r] = 0.f; rs[r] = 0.f; }
    f32x4 acc[8] = {};

    const int jbase = jh * 4096 + js * 2048;
    const int* arow = adj + (size_t)iw * 8192 + jbase + l * 4;
    const float* f2p = f2g + jbase + l * 4;
    const float* w2p = W2 + jbase + l * 4;

    i32x4 adjreg[16];
    f32x4 f2v, w2v;
    auto issue = [&](int c) {
        int jo = c * 256;
        f2v = *(const f32x4*)(f2p + jo);
        w2v = *(const f32x4*)(w2p + jo);
        #pragma unroll
        for (int r = 0; r < 16; ++r)
            adjreg[r] = __builtin_nontemporal_load(
                (const i32x4*)(arow + (size_t)r * 8192 + jo));
    };
    issue(0);

    const unsigned short* hBw = hB + (size_t)jbase * 128 + l * 8;  // wave's 2048-j segment
    const unsigned short* ap  = &tile[w][l & 15][(l >> 4) * 8];    // A-frag base

    for (int c = 0; c < 8; ++c) {
        // ---- consume chunk c: wg -> private LDS tile, den/rs lane-local (R8-verified) ----
        #pragma unroll
        for (int r = 0; r < 16; ++r) {
            i32x4 ad = adjreg[r];
            float g[4];
            float dsum = 0.f, rsum = 0.f;
            #pragma unroll
            for (int e = 0; e < 4; ++e) {
                float tt = f1r[r] + f2v[e];
                float lr = fmaxf(tt, ALPHA * tt);     // leakyrelu
                float ex = __expf(lr);
                float gg = (ad[e] != 0) ? ex : 0.0f;
                g[e] = gg;
                dsum += gg;
                rsum += (ad[e] != 0) ? w2v[e] : 0.0f;
            }
            den[r] += dsum;
            rs[r] += rsum;
            unsigned int p0 = bf16bits(g[0]) | ((unsigned int)bf16bits(g[1]) << 16);
            unsigned int p1 = bf16bits(g[2]) | ((unsigned int)bf16bits(g[3]) << 16);
            *(uint2*)&tile[w][r][l * 4] = make_uint2(p0, p1);
        }
        // ---- prefetch chunk c+1 adj/scalars ----
        if (c < 7) issue(c + 1);

        // ---- MFMA chunk c: A from private LDS, B double-buffered (R8-verified) ----
        const unsigned short* bp = hBw + (size_t)c * 32768;
        bf16x8 bbuf[2][8];
        #pragma unroll
        for (int ft = 0; ft < 8; ++ft)
            bbuf[0][ft] = *(const bf16x8*)(bp + ft * 512);
        #pragma unroll
        for (int ksl = 0; ksl < 8; ++ksl) {
            int cur = ksl & 1;
            if (ksl < 7) {
                const unsigned short* bk = bp + (size_t)(ksl + 1) * 4096;
                #pragma unroll
                for (int ft = 0; ft < 8; ++ft)
                    bbuf[cur ^ 1][ft] = *(const bf16x8*)(bk + ft * 512);
            }
            bf16x8 af = *(const bf16x8*)(ap + ksl * 32);
            #pragma unroll
            for (int ft = 0; ft < 8; ++ft)
                acc[ft] = __builtin_amdgcn_mfma_f32_16x16x32_bf16(af, bbuf[cur][ft], acc[ft], 0, 0, 0);
        }
    }

    // ---- lane reduction of den/rs -> den_s/rs_s ----
    #pragma unroll
    for (int r = 0; r < 16; ++r) {
        float d = den[r], rr = rs[r];
        #pragma unroll
        for (int off = 1; off < 64; off <<= 1) {
            d += __shfl_xor(d, off);
            rr += __shfl_xor(rr, off);
        }
        if (l == 0) { den_s[w][r] = d; rs_s[w][r] = rr; }
    }

    // ---- barrier BEFORE reusing tile as float buffer (race-fix, R8 lesson) ----
    __syncthreads();

    // ---- pairwise js reduction: js=1 waves dump acc, js=0 add ----
    float* fb = (float*)&tile[0][0][0];
    float* av = (float*)acc;
    if (js == 1) {
        float* dst = fb + (size_t)mg * 2048;
        #pragma unroll
        for (int j = 0; j < 32; ++j) dst[j * 64 + l] = av[j];
    }
    __syncthreads();

    if (js == 0) {
        const float* srcp = fb + (size_t)mg * 2048;
        #pragma unroll
        for (int j = 0; j < 32; ++j) av[j] += srcp[j * 64 + l];
        int q = l >> 4, col = l & 15;
        float* hpb = hp_part + ((size_t)jh * 8192 + iw) * 128;
        #pragma unroll
        for (int ft = 0; ft < 8; ++ft) {
            #pragma unroll
            for (int reg = 0; reg < 4; ++reg) {
                int row = q * 4 + reg;
                __builtin_nontemporal_store(acc[ft][reg],
                    hpb + (size_t)row * 128 + ft * 16 + col);
            }
        }
        if (l < 16)
            den_part[(size_t)jh * 8192 + iw + l] = den_s[w][l] + den_s[w + 1][l];
    } else if (w == 1) {
        // out-path partial: sum_i rs[i] * x[i][:] over this block's 64 rows (linear in rs)
        float px = 0.f, py = 0.f;
        for (int r = 0; r < 64; ++r) {
            int mgr = r >> 4;
            float rm = rs_s[mgr * 2][r & 15] + rs_s[mgr * 2 + 1][r & 15];
            const float* xr = x + (size_t)(i0 + r) * 128;
            px += rm * xr[l];
            py += rm * xr[l + 64];
        }
        atomicAdd(ws_acc + l, px);
        atomicAdd(ws_acc + l + 64, py);
    }
}

// ---------- Kernel 2b: merge j-half partials, normalize (R12-proven) ----------
__global__ __launch_bounds__(256) void gat_norm(
    const float* __restrict__ hp_part, const float* __restrict__ den_part,
    float* __restrict__ hp)
{
    int t = threadIdx.x;
    int row = blockIdx.x * 32 + (t >> 3);
    int f0 = (t & 7) * 16;
    float d = den_part[row] + den_part[8192 + row];
    float inv = (d != 0.f) ? 1.0f / d : 0.f;
    const f32x4* p0 = (const f32x4*)(hp_part + (size_t)row * 128 + f0);
    const f32x4* p1 = (const f32x4*)(hp_part + (size_t)(8192 + row) * 128 + f0);
    f32x4* o = (f32x4*)(hp + (size_t)row * 128 + f0);
    #pragma unroll
    for (int k = 0; k < 4; ++k) {
        f32x4 v = (p0[k] + p1[k]);
        o[k] = v * inv;
    }
}

// ---------- Kernel 3: elu epilogue ----------
__global__ __launch_bounds__(128) void gat_finish(const float* __restrict__ ws_acc,
                                                  float* __restrict__ out)
{
    int t = threadIdx.x;
    float v = ws_acc[t];
    out[t] = (v > 0.f) ? v : (__expf(v) - 1.0f);
}

extern "C" void kernel_launch(void* const* d_in, const int* in_sizes, int n_in,
                              void* d_out, int out_size, void* d_ws, size_t ws_size,
                              hipStream_t stream) {
    const float* x   = (const float*)d_in[0];
    const int*   adj = (const int*)d_in[1];
    const float* W   = (const float*)d_in[2];
    const float* a   = (const float*)d_in[3];
    const float* W2  = (const float*)d_in[4];
    float* out = (float*)d_out;              // [0:128] elu out, [128:] h_prime [8192][128]

    float* wsf     = (float*)d_ws;
    float* ws_acc  = wsf;                        // 128 floats
    float* f1      = wsf + 128;                  // 8192
    float* f2      = wsf + 128 + 8192;           // 8192
    unsigned short* hB = (unsigned short*)(wsf + 128 + 2 * 8192);  // 1M shorts (2 MB)
    float* hp_part = wsf + 128 + 2 * 8192 + 524288;   // 2*8192*128 f32 = 8 MB
    float* den_part = hp_part + 2 * 8192 * 128;       // 2*8192 f32

    gat_prep<<<256, 256, 0, stream>>>(x, W, a, f1, f2, hB, ws_acc);
    gat_main<<<256, 512, 0, stream>>>(adj, x, W2, f1, f2, hB, hp_part, den_part, ws_acc);
    gat_norm<<<256, 256, 0, stream>>>(hp_part, den_part, out + 128);
    gat_finish<<<1, 128, 0, stream>>>(ws_acc, out);
}